// Round 7
// baseline (43.331 us; speedup 1.0000x reference)
//
#include <hip/hip_runtime.h>
#include <hip/hip_fp16.h>

#define NCLS 21
#define HW (512 * 512)
#define HW4 (HW / 4)                   // 65536 float4 per (b,c) plane
#define NB 8
#define NPIX (NB * HW)                 // 2097152
#define NPIX4 (NPIX / 4)               // 524288 pixel-quads
#define NBLK (NPIX4 / 256)             // 2048 blocks (pass1 & pass2)
#define TOTAL_ELEMS ((long long)NPIX * NCLS)

// ws layout:
//   [0     ..  8K)  float bmin[2048]
//   [8K    .. 16K)  float bmax[2048]
//   [16K   .. 32K)  double partial[2048]
//   [64K   .. +8MB) packed half2 per pixel (x=sigma_raw fp16, y=S fp16)

union HU { __half2 h; unsigned int u; };

// Pass 1: single float4 logits read; softmax stats + focal; packed (sig,S)
// fp16 x4 per thread; per-block min/max partials. No atomics, no fences.
__global__ __launch_bounds__(256) void lasd_pass1(const float4* __restrict__ in4,
                                                  const int4* __restrict__ tgt4,
                                                  uint4* __restrict__ sigS4,
                                                  float* __restrict__ bmin,
                                                  float* __restrict__ bmax) {
    int j = blockIdx.x * 256 + threadIdx.x;    // pixel-quad index
    int b = j >> 16;                            // j / HW4
    int p4 = j & (HW4 - 1);
    const float4* base = in4 + ((size_t)(b * NCLS) << 16) + p4;

    float4 x[NCLS];
    float s[4] = {0.f, 0.f, 0.f, 0.f};
#pragma unroll
    for (int c = 0; c < NCLS; ++c) {
        x[c] = base[(size_t)c << 16];
        s[0] += __expf(x[c].x); s[1] += __expf(x[c].y);
        s[2] += __expf(x[c].z); s[3] += __expf(x[c].w);
    }
    float inv[4], ls[4];
#pragma unroll
    for (int k = 0; k < 4; ++k) { inv[k] = 1.0f / s[k]; ls[k] = __logf(s[k]); }

    int4 tt = tgt4[j];
    int t[4] = {tt.x, tt.y, tt.z, tt.w};

    float sp[4] = {0,0,0,0}, q[4] = {0,0,0,0}, F[4] = {0,0,0,0}, ft[4] = {0,0,0,0};
#pragma unroll
    for (int c = 0; c < NCLS; ++c) {
        float xs[4] = {x[c].x, x[c].y, x[c].z, x[c].w};
#pragma unroll
        for (int k = 0; k < 4; ++k) {
            float p = __expf(xs[k]) * inv[k] + 1e-8f;        // softmax + EPS
            float om = 1.0f - p;
            float f = -0.25f * om * om * (xs[k] - ls[k]);    // log p = x - log s
            sp[k] += p;
            q[k] = fmaf(p, p, q[k]);
            F[k] += f;
            if (c == t[k]) ft[k] = f;
        }
    }

    float lmin = 1e30f, lmax = -1e30f;
    unsigned int pk[4];
#pragma unroll
    for (int k = 0; k < 4; ++k) {
        float var = fmaxf(q[k] - sp[k] * sp[k] * (1.0f / 21.0f), 0.0f);
        float sg = sqrtf(var * (1.0f / 20.0f));              // ddof=1
        float S = ft[k] + 1e-6f * F[k];
        HU h;
        h.h.x = __float2half_rn(sg);
        h.h.y = __float2half_rn(S);
        pk[k] = h.u;
        float r = __half2float(h.h.x);   // min/max over ROUNDED sigma
        lmin = fminf(lmin, r);
        lmax = fmaxf(lmax, r);
    }
    uint4 st; st.x = pk[0]; st.y = pk[1]; st.z = pk[2]; st.w = pk[3];
    sigS4[j] = st;

#pragma unroll
    for (int off = 32; off > 0; off >>= 1) {
        lmin = fminf(lmin, __shfl_down(lmin, off));
        lmax = fmaxf(lmax, __shfl_down(lmax, off));
    }
    __shared__ float smn[4], smx[4];
    int wid = threadIdx.x >> 6, lane = threadIdx.x & 63;
    if (lane == 0) { smn[wid] = lmin; smx[wid] = lmax; }
    __syncthreads();
    if (threadIdx.x == 0) {
        bmin[blockIdx.x] = fminf(fminf(smn[0], smn[1]), fminf(smn[2], smn[3]));
        bmax[blockIdx.x] = fmaxf(fmaxf(smx[0], smx[1]), fmaxf(smx[2], smx[3]));
    }
}

// Pass 2: redundant per-block min/max reduce (8 KB from L2/L3, no fence);
// normalize sigma -> out; per-block beta*S partial sums.
__global__ __launch_bounds__(256) void lasd_pass2(const uint4* __restrict__ sigS4,
                                                  float* __restrict__ out,     // [1..] sigma
                                                  const float4* __restrict__ bmin4,
                                                  const float4* __restrict__ bmax4,
                                                  double* __restrict__ partial) {
    const int wid = threadIdx.x >> 6, lane = threadIdx.x & 63;

    float a = 1e30f, z = -1e30f;
#pragma unroll
    for (int k = 0; k < NBLK / 4 / 256; ++k) {           // 2048 floats = 512 float4
        float4 v = bmin4[threadIdx.x + k * 256];
        float4 w = bmax4[threadIdx.x + k * 256];
        a = fminf(a, fminf(fminf(v.x, v.y), fminf(v.z, v.w)));
        z = fmaxf(z, fmaxf(fmaxf(w.x, w.y), fmaxf(w.z, w.w)));
    }
#pragma unroll
    for (int off = 32; off > 0; off >>= 1) {
        a = fminf(a, __shfl_down(a, off));
        z = fmaxf(z, __shfl_down(z, off));
    }
    __shared__ float smn[4], smx[4];
    __shared__ float s_min, s_rinv;
    if (lane == 0) { smn[wid] = a; smx[wid] = z; }
    __syncthreads();
    if (threadIdx.x == 0) {
        float mn = fminf(fminf(smn[0], smn[1]), fminf(smn[2], smn[3]));
        float mx = fmaxf(fmaxf(smx[0], smx[1]), fmaxf(smx[2], smx[3]));
        s_min = mn;
        s_rinv = 1.0f / (mx - mn);
    }
    __syncthreads();
    float smin = s_min, rinv = s_rinv;

    int j = blockIdx.x * 256 + threadIdx.x;              // pixel-quad index
    uint4 pk = sigS4[j];
    unsigned int w[4] = {pk.x, pk.y, pk.z, pk.w};
    float lsum = 0.0f;
#pragma unroll
    for (int k = 0; k < 4; ++k) {
        HU cv; cv.u = w[k];
        float sg = __half2float(cv.h.x);
        float S = __half2float(cv.h.y);
        float t = (sg - smin) * rinv;
        out[1 + 4 * j + k] = t;
        lsum += (__expf(-t) + 1.0f) * S;
    }
#pragma unroll
    for (int off = 32; off > 0; off >>= 1) lsum += __shfl_down(lsum, off);
    __shared__ float shs[4];
    if (lane == 0) shs[wid] = lsum;
    __syncthreads();
    if (threadIdx.x == 0)
        partial[blockIdx.x] = (double)(shs[0] + shs[1] + shs[2] + shs[3]);
}

// Final: sum 2048 doubles -> loss
__global__ __launch_bounds__(256) void lasd_finish(const double* __restrict__ partial,
                                                   float* __restrict__ loss_out) {
    double acc = 0.0;
#pragma unroll
    for (int k = 0; k < NBLK / 256; ++k)
        acc += partial[threadIdx.x + k * 256];
#pragma unroll
    for (int off = 32; off > 0; off >>= 1) acc += __shfl_down(acc, off);
    __shared__ double sh[4];
    int wid = threadIdx.x >> 6, lane = threadIdx.x & 63;
    if (lane == 0) sh[wid] = acc;
    __syncthreads();
    if (threadIdx.x == 0)
        loss_out[0] = (float)((sh[0] + sh[1] + sh[2] + sh[3]) / (double)TOTAL_ELEMS);
}

extern "C" void kernel_launch(void* const* d_in, const int* in_sizes, int n_in,
                              void* d_out, int out_size, void* d_ws, size_t ws_size,
                              hipStream_t stream) {
    const float4* logits4 = (const float4*)d_in[0];
    const int4* target4 = (const int4*)d_in[1];
    float* out = (float*)d_out;                  // out[0]=loss, out[1..]=sigma
    char* ws = (char*)d_ws;

    float* bmin = (float*)ws;                    // 2048 f
    float* bmax = (float*)(ws + 8192);           // 2048 f
    double* partial = (double*)(ws + 16384);     // 2048 d
    uint4* sigS = (uint4*)(ws + 65536);          // 8 MB packed

    lasd_pass1<<<NBLK, 256, 0, stream>>>(logits4, target4, sigS, bmin, bmax);
    lasd_pass2<<<NBLK, 256, 0, stream>>>((const uint4*)sigS, out,
                                         (const float4*)bmin, (const float4*)bmax,
                                         partial);
    lasd_finish<<<1, 256, 0, stream>>>(partial, out);
}